// Round 6
// baseline (240.821 us; speedup 1.0000x reference)
//
#include <hip/hip_runtime.h>
#include <hip/hip_bf16.h>

#define NN 268
#define NE 8192
#define KP 288   // padded node dim (268 -> 288)

typedef short short8 __attribute__((ext_vector_type(8)));   // 8 bf16 = 4 VGPR
typedef short short4v __attribute__((ext_vector_type(4)));  // 4 bf16 = 8B
typedef float f32x4 __attribute__((ext_vector_type(4)));

__device__ __forceinline__ short f2bf(float f) {
  __hip_bfloat16 h = __float2bfloat16(f);
  return *reinterpret_cast<short*>(&h);
}

// ---------------------------------------------------------------------------
// Workspace (bytes). Peak 51,444,736 (WbT region retained but now unused).
//   OFF_DINV  dinv  f32 [128][272]           139,264
//   OFF_ARENA Y2t   bf16[128][64][288]     4,718,592  (gemm1 out, mega in)
//   OFF_WC1BT Wc1bT bf16[112][288]            64,512
//   OFF_W4BT  W4bT  bf16[96][64]              12,288
//   OFF_LB    Lb    bf16[128][272][288]   20,054,016
//   OFF_Y     Y     f32 [128][268][192]   26,345,472
// Math chain BIT-IDENTICAL to round-1. Round-6 changes are execution only:
//   - prep shrunk to degree-only (weight conv -> build_gemm1 tail family;
//     gemm1 stages B straight from fp32 W1, so WbT is dead)
//   - gemm1 k-loop register prefetch (round-3 staging, verified passing)
//   - mega at 1024 threads (16 waves: phase rounds halved, 2x TLP)
// ---------------------------------------------------------------------------
#define OFF_DINV  0
#define OFF_ARENA 139264
#define ARENA_SLAB_S 18432   // shorts per graph: Y2t [64][288]
#define OFF_WC1BT 4968448
#define OFF_W4BT  5032960
#define OFF_LB    5045248
#define OFF_Y     25099264

// ---------------------------------------------------------------------------
// K1: per-graph degree -> dinv. 128 blocks.
// ---------------------------------------------------------------------------
__global__ __launch_bounds__(256) void k_deg(
    const int* __restrict__ ei1, const float* __restrict__ ea1,
    const int* __restrict__ ei2, const float* __restrict__ ea2,
    float* __restrict__ dinv) {
  int t = threadIdx.x;
  int g = blockIdx.x;
  const int* ei = (g < 64) ? (ei1 + (size_t)g * 2 * NE) : (ei2 + (size_t)(g - 64) * 2 * NE);
  const float* ea = (g < 64) ? (ea1 + (size_t)g * NE) : (ea2 + (size_t)(g - 64) * NE);
  __shared__ unsigned degL[NN];
  for (int n = t; n < NN; n += 256) degL[n] = 0u;
  __syncthreads();
#pragma unroll 4
  for (int e = t; e < NE; e += 256) {
    int s = ei[e], d = ei[NE + e];
    float w = ea[e];
    if (s != d) atomicAdd(&degL[s], (unsigned)lrintf(w * 1048576.f));
  }
  __syncthreads();
  for (int n = t; n < 272; n += 256) {
    float r = 0.f;
    if (n < NN) {
      unsigned v = degL[n];
      if (v) r = rsqrtf((float)v * (1.f / 1048576.f));
    }
    dinv[(size_t)g * 272 + n] = r;
  }
}

// ---------------------------------------------------------------------------
// K2: fused Laplacian build + gemm1 + weight-conv tail. 1814 blocks.
//  [0,640):     gemm1 (MFMA) with register prefetch; B staged directly from
//               fp32 W1 (transpose-scatter, identical rounding to old WbT).
//  [640,1664):  Laplacian 34-row tiles (round-1 verbatim).
//  [1664,1814): Wc1bT / W4bT conversion (consumed by k_mega, next launch).
// ---------------------------------------------------------------------------
__global__ __launch_bounds__(256) void k_build_gemm1(
    const int* __restrict__ ei1, const float* __restrict__ ea1,
    const int* __restrict__ ei2, const float* __restrict__ ea2,
    const float* __restrict__ dinv_all, short* __restrict__ Lb,
    const float* __restrict__ x1, const float* __restrict__ x2,
    const float* __restrict__ W1, const float* __restrict__ Wc1,
    const float* __restrict__ W4, float* __restrict__ Y,
    short* __restrict__ Y2t, short* __restrict__ Wc1bT,
    short* __restrict__ W4bT) {
  __shared__ __align__(16) char smem[34 * 288 * 4 + 272 * 4];  // 40,256 B
  int t = threadIdx.x;
  int bx = blockIdx.x;
  if (bx < 640) {
    // ===================== gemm1 (MFMA, prefetched) =====================
    int xcd = bx & 7, rest = bx >> 3;       // rest 0..79
    int g = xcd + 8 * (rest / 5);           // graph on XCD g&7
    int m0 = (rest % 5) * 64;
    const float* A32 = (g < 64) ? (x1 + (size_t)g * NN * 268)
                                : (x2 + (size_t)(g - 64) * NN * 268);
    float* Yg = Y + (size_t)g * NN * 192;
    short* Y2tg = Y2t + (size_t)g * ARENA_SLAB_S;
    short (*As)[40] = (short(*)[40])smem;                  //  5,120 B
    short (*Bs)[40] = (short(*)[40])(smem + 5120);         // 15,360 B
    int w = t >> 6, lane = t & 63;
    int quad = lane >> 4, l16 = lane & 15;
    int mh = w & 1, nh = w >> 1;
    f32x4 acc[2][6];
#pragma unroll
    for (int mi = 0; mi < 2; ++mi)
#pragma unroll
      for (int ni = 0; ni < 6; ++ni) acc[mi][ni] = (f32x4){0.f, 0.f, 0.f, 0.f};

    int sr = t >> 2, sko = (t & 3) * 8;
    float4 pva, pvb, pb0[3], pb1[3];
    auto loadA = [&](int K0) {
      int row = m0 + sr, k = K0 + sko;
      pva = make_float4(0.f, 0.f, 0.f, 0.f); pvb = pva;
      if (row < NN && k < 268) pva = *(const float4*)(A32 + (size_t)row * 268 + k);
      if (row < NN && k + 4 < 268) pvb = *(const float4*)(A32 + (size_t)row * 268 + k + 4);
    };
    auto loadB = [&](int K0) {
      // 768 units: uid -> (kp 0..15 k-pair, n0 n-quad). W1 [3][268][64].
#pragma unroll
      for (int u = 0; u < 3; ++u) {
        int uid = t + u * 256;
        int kp = uid & 15, n0 = (uid >> 4) * 4;
        int kb = n0 >> 6, j0 = n0 & 63;
        int k = K0 + kp * 2;
        pb0[u] = (k < 268) ? *(const float4*)(W1 + ((size_t)kb * 268 + k) * 64 + j0)
                           : make_float4(0.f, 0.f, 0.f, 0.f);
        pb1[u] = (k + 1 < 268) ? *(const float4*)(W1 + ((size_t)kb * 268 + k + 1) * 64 + j0)
                               : make_float4(0.f, 0.f, 0.f, 0.f);
      }
    };
    loadA(0); loadB(0);
    for (int k0 = 0; k0 < KP; k0 += 32) {
      {
        short8 s;
        const float* fa = (const float*)&pva;
        const float* fb = (const float*)&pvb;
#pragma unroll
        for (int j = 0; j < 4; ++j) { s[j] = f2bf(fa[j]); s[4 + j] = f2bf(fb[j]); }
        *(short8*)(&As[sr][sko]) = s;
      }
#pragma unroll
      for (int u = 0; u < 3; ++u) {
        int uid = t + u * 256;
        int kp = uid & 15, n0 = (uid >> 4) * 4;
        const float* f0 = (const float*)&pb0[u];
        const float* f1 = (const float*)&pb1[u];
#pragma unroll
        for (int jj = 0; jj < 4; ++jj) {
          unsigned lo = (unsigned short)f2bf(f0[jj]);
          unsigned hi = (unsigned short)f2bf(f1[jj]);
          *(unsigned*)(&Bs[n0 + jj][kp * 2]) = lo | (hi << 16);
        }
      }
      __syncthreads();
      if (k0 + 32 < KP) { loadA(k0 + 32); loadB(k0 + 32); }  // hides under MFMA
      short8 af[2], bfr[6];
#pragma unroll
      for (int mi = 0; mi < 2; ++mi)
        af[mi] = *(const short8*)(&As[(mh * 2 + mi) * 16 + l16][quad * 8]);
#pragma unroll
      for (int ni = 0; ni < 6; ++ni)
        bfr[ni] = *(const short8*)(&Bs[(nh * 6 + ni) * 16 + l16][quad * 8]);
#pragma unroll
      for (int mi = 0; mi < 2; ++mi)
#pragma unroll
        for (int ni = 0; ni < 6; ++ni)
          acc[mi][ni] = __builtin_amdgcn_mfma_f32_16x16x32_bf16(af[mi], bfr[ni], acc[mi][ni], 0, 0, 0);
      __syncthreads();
    }
    // C/D: col = lane&15, row = quad*4 + reg
#pragma unroll
    for (int mi = 0; mi < 2; ++mi) {
      int rbase = m0 + (mh * 2 + mi) * 16 + quad * 4;
#pragma unroll
      for (int reg = 0; reg < 4; ++reg) {
        int row = rbase + reg;
        if (row < NN) {
#pragma unroll
          for (int ni = 0; ni < 6; ++ni) {
            int col = (nh * 6 + ni) * 16 + l16;
            Yg[(size_t)row * 192 + col] = acc[mi][ni][reg];
          }
        }
      }
      if (rbase < NN) {  // rbase % 4 == 0, never straddles 268
#pragma unroll
        for (int ni = 0; ni < 6; ++ni) {
          int col = (nh * 6 + ni) * 16 + l16;
          if (col >= 128) {
            short4v p;
#pragma unroll
            for (int reg = 0; reg < 4; ++reg) p[reg] = f2bf(acc[mi][ni][reg]);
            *(short4v*)(Y2tg + (size_t)(col - 128) * KP + rbase) = p;
          }
        }
      }
    }
  } else if (bx < 1664) {
    // ===================== Laplacian build =====================
    int l = bx - 640;                // 0..1023 = 8 xcd * 16 g * 8 tiles
    int xcd = l & 7, rest = l >> 3;  // rest 0..127
    int g = xcd + 8 * (rest & 15);
    int tile = rest >> 4;            // 0..7
    int r0 = tile * 34;
    const int* ei = (g < 64) ? (ei1 + (size_t)g * 2 * NE) : (ei2 + (size_t)(g - 64) * 2 * NE);
    const float* ea = (g < 64) ? (ea1 + (size_t)g * NE) : (ea2 + (size_t)(g - 64) * NE);
    int* LrowI = (int*)smem;                      // 34*288 ints = 39,168 B
    float* dv = (float*)(smem + 39168);           // 272 floats
    for (int i = t; i < 34 * 288; i += 256) LrowI[i] = 0;
    for (int i = t; i < 272; i += 256) dv[i] = dinv_all[(size_t)g * 272 + i];
    __syncthreads();
#pragma unroll 8
    for (int e = t; e < NE; e += 256) {
      int d = ei[NE + e];
      int s = ei[e];
      float w = ea[e];
      if (d >= r0 && d < r0 + 34 && s != d) {
        atomicAdd(&LrowI[(d - r0) * 288 + s],
                  (int)lrintf(-dv[s] * w * dv[d] * 16777216.f));  // native ds_add
      }
    }
    __syncthreads();
    short* Lbg = Lb + (size_t)g * 272 * KP + (size_t)r0 * KP;
    for (int i = t; i < 34 * 288; i += 256)
      Lbg[i] = f2bf((float)LrowI[i] * (1.f / 16777216.f));
  } else {
    // ===================== weight conversion tail ==========================
    int idx = (bx - 1664) * 256 + t;  // 0..38399
    if (idx < 112 * KP) {
      int n = idx / KP, k = idx - n * KP;
      float v = (n < 100 && k < 268) ? Wc1[(size_t)k * 100 + n] : 0.f;
      Wc1bT[idx] = f2bf(v);
    } else {
      int i4 = idx - 112 * KP;       // 0..6143
      int n = i4 >> 6, k = i4 & 63;  // n in [0,96), k in [0,64)
      W4bT[i4] = f2bf(W4[(((size_t)(n >> 5)) * 64 + k) * 32 + (n & 31)]);
    }
  }
}

// ---------------------------------------------------------------------------
// K3: MEGA — whole post-gemm1 chain per graph in ONE block. Round-6: 1024
// threads (16 waves, 4/SIMD): phase rounds halved vs round 5, 2x TLP.
// Register double-buffer of global L A-fragments + residual-Y prefetch kept.
// 128 blocks, 111,616 B LDS (1 block/CU). Phases (identical math):
//   P0 Y2t->LDS   P1 Ut=bf16(Y1+2*L@Y2)   P2 H1=relu(Y0-Y2+L@Ut+b1)
//   P3 Yb=H1@W4 -> Yg f32 + Yb2t LDS      P4 Ut2=bf16(Yb1+2*L@Yb2)
//   P5 H2=relu(Yb0-Yb2+L@Ut2+b4)          P6 classifier -> out
// ---------------------------------------------------------------------------
#define SP 296
#define YT2_O  0
#define H1N_O  0
#define UT_O   40960
#define UT2_O  40960
#define H2T_O  59904
#define W4S_O  78848
#define YBT_O  92672
#define Z1_O   0
#define W2S_O  14848
#define Z2_O   78848
#define W3S_O  87040
#define SM_SZ  111616
#define NW     16      // waves per mega block
#define NTHR   1024

__device__ __forceinline__ void load_a9(const short* __restrict__ Lbg,
                                        int mt, int l16, int quad, short8* a9) {
  const short* Arow = Lbg + (size_t)(mt * 16 + l16) * KP + quad * 8;
#pragma unroll
  for (int k = 0; k < 9; ++k) a9[k] = *(const short8*)(Arow + k * 32);
}

template <int NTN>
__device__ __forceinline__ void cheb_mm_pre(const short8* a9,
                                            const char* B0, int l16, int quad,
                                            f32x4* acc) {
#pragma unroll
  for (int k = 0; k < 9; ++k) {
#pragma unroll
    for (int nt = 0; nt < NTN; ++nt) {
      short8 bf = *(const short8*)(B0 +
          ((size_t)(nt * 16 + l16) * SP + k * 32 + quad * 8) * 2);
      acc[nt] = __builtin_amdgcn_mfma_f32_16x16x32_bf16(a9[k], bf, acc[nt], 0, 0, 0);
    }
  }
}

__global__ __launch_bounds__(NTHR, 1) void k_mega(
    const short* __restrict__ Lb, const short* __restrict__ arena,
    float* __restrict__ Y, const short* __restrict__ W4bT,
    const short* __restrict__ Wc1bT,
    const float* __restrict__ b1, const float* __restrict__ b4,
    const float* __restrict__ bc1, const float* __restrict__ Wc2,
    const float* __restrict__ bc2, const float* __restrict__ Wc3,
    const float* __restrict__ bc3, float* __restrict__ out) {
  __shared__ __align__(16) char sm[SM_SZ];
  int g = blockIdx.x;
  int t = threadIdx.x;
  int w = t >> 6, lane = t & 63;
  int quad = lane >> 4, l16 = lane & 15;
  const short* Lbg = Lb + (size_t)g * 272 * KP;
  const short* Y2tg = arena + (size_t)g * ARENA_SLAB_S;
  float* Yg = Y + (size_t)g * NN * 192;

  // ---- P0: Y2t -> LDS [64][SP]; cols >=268 forced to 0 (poison-safe) ----
  for (int i = t; i < 64 * 37; i += NTHR) {
    int r = i / 37, c = (i - r * 37) * 8;
    short8 v = {0, 0, 0, 0, 0, 0, 0, 0};
    if (c < 264) {
      v = *(const short8*)(Y2tg + (size_t)r * KP + c);
    } else if (c == 264) {
      v = *(const short8*)(Y2tg + (size_t)r * KP + 264);
      v[4] = 0; v[5] = 0; v[6] = 0; v[7] = 0;
    }
    *(short8*)(sm + YT2_O + ((size_t)r * SP + c) * 2) = v;
  }
  // zero Ut node-pad cols 268..287 (Ut region disjoint of Y2t)
  for (int i = t; i < 64 * 20; i += NTHR) {
    int f = i / 20, d = 268 + (i - f * 20);
    *(short*)(sm + UT_O + ((size_t)f * SP + d) * 2) = 0;
  }
  __syncthreads();

  // ---- P1: Ut[f][d] = bf16(Y1[d][f] + 2*(L@Y2)[d][f]) ----
  {
    short8 ac[9], an[9];
    int mt = w;
    if (mt < 17) load_a9(Lbg, mt, l16, quad, ac);
    for (; mt < 17; mt += NW) {
      if (mt + NW < 17) load_a9(Lbg, mt + NW, l16, quad, an);
      int dbase = mt * 16 + quad * 4;
      float yr[4][4];
      if (dbase < NN) {
#pragma unroll
        for (int nt = 0; nt < 4; ++nt)
#pragma unroll
          for (int reg = 0; reg < 4; ++reg)
            yr[nt][reg] = Yg[(size_t)(dbase + reg) * 192 + 64 + nt * 16 + l16];
      }
      f32x4 acc[4];
#pragma unroll
      for (int nt = 0; nt < 4; ++nt) acc[nt] = (f32x4){0.f, 0.f, 0.f, 0.f};
      cheb_mm_pre<4>(ac, sm + YT2_O, l16, quad, acc);
      if (dbase < NN) {
#pragma unroll
        for (int nt = 0; nt < 4; ++nt) {
          int f = nt * 16 + l16;
          short4v p;
#pragma unroll
          for (int reg = 0; reg < 4; ++reg)
            p[reg] = f2bf(yr[nt][reg] + 2.f * acc[nt][reg]);
          *(short4v*)(sm + UT_O + ((size_t)f * SP + dbase) * 2) = p;
        }
      }
      if (mt + NW < 17) {
#pragma unroll
        for (int k = 0; k < 9; ++k) ac[k] = an[k];
      }
    }
  }
  __syncthreads();

  // ---- P2: H1n[d][f] = relu(Y0 - Y2 + (L@Ut)[d][f] + b1[f]), stride 72 ----
  {
    short8 ac[9], an[9];
    int mt = w;
    if (mt < 17) load_a9(Lbg, mt, l16, quad, ac);
    for (; mt < 17; mt += NW) {
      if (mt + NW < 17) load_a9(Lbg, mt + NW, l16, quad, an);
      int dbase = mt * 16 + quad * 4;
      float yr0[4][4], yr2[4][4];
      if (dbase < NN) {
#pragma unroll
        for (int nt = 0; nt < 4; ++nt)
#pragma unroll
          for (int reg = 0; reg < 4; ++reg) {
            int f = nt * 16 + l16;
            yr0[nt][reg] = Yg[(size_t)(dbase + reg) * 192 + f];
            yr2[nt][reg] = Yg[(size_t)(dbase + reg) * 192 + 128 + f];
          }
      }
      f32x4 acc[4];
#pragma unroll
      for (int nt = 0; nt < 4; ++nt) acc[nt] = (f32x4){0.f, 0.f, 0.f, 0.f};
      cheb_mm_pre<4>(ac, sm + UT_O, l16, quad, acc);
      if (dbase < NN) {
#pragma unroll
        for (int nt = 0; nt < 4; ++nt) {
          int f = nt * 16 + l16;
          float bb = b1[f];
#pragma unroll
          for (int reg = 0; reg < 4; ++reg) {
            int d = dbase + reg;
            float v = yr0[nt][reg] - yr2[nt][reg] + acc[nt][reg] + bb;
            *(short*)(sm + H1N_O + ((size_t)d * 72 + f) * 2) = f2bf(fmaxf(v, 0.f));
          }
        }
      }
      if (mt + NW < 17) {
#pragma unroll
        for (int k = 0; k < 9; ++k) ac[k] = an[k];
      }
    }
  }
  __syncthreads();

  // ---- P3: Yb^T[c][d] = (H1 @ W4)[d][c]; c<64 -> Yg[d][c] f32,
  //          c>=64 -> Yg[d][c+96] f32 + YBT (Yb2t bf16) ----
  for (int i = t; i < 96 * 8; i += NTHR) {  // stage W4s [96][72]
    int r = i >> 3, ko = (i & 7) * 8;
    *(short8*)(sm + W4S_O + ((size_t)r * 72 + ko) * 2) =
        *(const short8*)(W4bT + r * 64 + ko);
  }
  for (int i = t; i < 32 * 20; i += NTHR) { // zero YBT node-pads
    int f = i / 20, d = 268 + (i - f * 20);
    *(short*)(sm + YBT_O + ((size_t)f * SP + d) * 2) = 0;
  }
  __syncthreads();
  for (int id = w; id < 102; id += NW) {    // 6 c-tiles x 17 d-tiles
    int mt = id / 17, nt = id - mt * 17;
    f32x4 a1 = (f32x4){0.f, 0.f, 0.f, 0.f};
#pragma unroll
    for (int kc = 0; kc < 2; ++kc) {
      short8 af = *(const short8*)(sm + W4S_O +
          ((size_t)(mt * 16 + l16) * 72 + kc * 32 + quad * 8) * 2);
      short8 bf = *(const short8*)(sm + H1N_O +
          ((size_t)(nt * 16 + l16) * 72 + kc * 32 + quad * 8) * 2);
      a1 = __builtin_amdgcn_mfma_f32_16x16x32_bf16(af, bf, a1, 0, 0, 0);
    }
    int d = nt * 16 + l16;
    if (d < NN) {
      int c0 = mt * 16 + quad * 4;
#pragma unroll
      for (int reg = 0; reg < 4; ++reg) {
        int c = c0 + reg;
        float a = a1[reg];
        Yg[(size_t)d * 192 + ((c < 64) ? c : c + 96)] = a;
        if (c >= 64)
          *(short*)(sm + YBT_O + ((size_t)(c - 64) * SP + d) * 2) = f2bf(a);
      }
    }
  }
  __syncthreads();

  // ---- P4: Ut2[f][d] = bf16(Yb1[d][f] + 2*(L@Yb2)[d][f]) ----
  for (int i = t; i < 32 * 20; i += NTHR) {
    int f = i / 20, d = 268 + (i - f * 20);
    *(short*)(sm + UT2_O + ((size_t)f * SP + d) * 2) = 0;
  }
  __syncthreads();
  {
    short8 ac[9], an[9];
    int mt = w;
    if (mt < 17) load_a9(Lbg, mt, l16, quad, ac);
    for (; mt < 17; mt += NW) {
      if (mt + NW < 17) load_a9(Lbg, mt + NW, l16, quad, an);
      int dbase = mt * 16 + quad * 4;
      float yr[2][4];
      if (dbase < NN) {
#pragma unroll
        for (int nt = 0; nt < 2; ++nt)
#pragma unroll
          for (int reg = 0; reg < 4; ++reg)
            yr[nt][reg] = Yg[(size_t)(dbase + reg) * 192 + 32 + nt * 16 + l16];
      }
      f32x4 acc[2];
#pragma unroll
      for (int nt = 0; nt < 2; ++nt) acc[nt] = (f32x4){0.f, 0.f, 0.f, 0.f};
      cheb_mm_pre<2>(ac, sm + YBT_O, l16, quad, acc);
      if (dbase < NN) {
#pragma unroll
        for (int nt = 0; nt < 2; ++nt) {
          int f = nt * 16 + l16;
          short4v p;
#pragma unroll
          for (int reg = 0; reg < 4; ++reg)
            p[reg] = f2bf(yr[nt][reg] + 2.f * acc[nt][reg]);
          *(short4v*)(sm + UT2_O + ((size_t)f * SP + dbase) * 2) = p;
        }
      }
      if (mt + NW < 17) {
#pragma unroll
        for (int k = 0; k < 9; ++k) ac[k] = an[k];
      }
    }
  }
  __syncthreads();

  // ---- P5: H2T[f][d] = relu(Yb0 - Yb2 + (L@Ut2)[d][f] + b4[f]) ----
  for (int i = t; i < 32 * 20; i += NTHR) {
    int f = i / 20, d = 268 + (i - f * 20);
    *(short*)(sm + H2T_O + ((size_t)f * SP + d) * 2) = 0;
  }
  __syncthreads();
  {
    short8 ac[9], an[9];
    int mt = w;
    if (mt < 17) load_a9(Lbg, mt, l16, quad, ac);
    for (; mt < 17; mt += NW) {
      if (mt + NW < 17) load_a9(Lbg, mt + NW, l16, quad, an);
      int dbase = mt * 16 + quad * 4;
      float yr0[2][4], yr2[2][4];
      if (dbase < NN) {
#pragma unroll
        for (int nt = 0; nt < 2; ++nt)
#pragma unroll
          for (int reg = 0; reg < 4; ++reg) {
            int f = nt * 16 + l16;
            yr0[nt][reg] = Yg[(size_t)(dbase + reg) * 192 + f];
            yr2[nt][reg] = Yg[(size_t)(dbase + reg) * 192 + 160 + f];
          }
      }
      f32x4 acc[2];
#pragma unroll
      for (int nt = 0; nt < 2; ++nt) acc[nt] = (f32x4){0.f, 0.f, 0.f, 0.f};
      cheb_mm_pre<2>(ac, sm + UT2_O, l16, quad, acc);
      if (dbase < NN) {
#pragma unroll
        for (int nt = 0; nt < 2; ++nt) {
          int f = nt * 16 + l16;
          float bb = b4[f];
          short4v p;
#pragma unroll
          for (int reg = 0; reg < 4; ++reg) {
            float v = yr0[nt][reg] - yr2[nt][reg] + acc[nt][reg] + bb;
            p[reg] = f2bf(fmaxf(v, 0.f));
          }
          *(short4v*)(sm + H2T_O + ((size_t)f * SP + dbase) * 2) = p;
        }
      }
      if (mt + NW < 17) {
#pragma unroll
        for (int k = 0; k < 9; ++k) ac[k] = an[k];
      }
    }
  }
  __syncthreads();

  // ---- P6: classifier. L1: MFMA 32x112 K=288 (A=H2T LDS, B=Wc1bT global) ----
  for (int id = w; id < 14; id += NW) {     // 2 m-tiles x 7 n-tiles
    int mt = id & 1, nt = id >> 1;
    f32x4 a1 = (f32x4){0.f, 0.f, 0.f, 0.f};
#pragma unroll
    for (int k = 0; k < 9; ++k) {
      short8 af = *(const short8*)(sm + H2T_O +
          ((size_t)(mt * 16 + l16) * SP + k * 32 + quad * 8) * 2);
      short8 bf = *(const short8*)(Wc1bT + (size_t)(nt * 16 + l16) * KP + k * 32 + quad * 8);
      a1 = __builtin_amdgcn_mfma_f32_16x16x32_bf16(af, bf, a1, 0, 0, 0);
    }
    int col = nt * 16 + l16;
    if (col < 100) {
      float bb = bc1[col];
      int r0 = mt * 16 + quad * 4;
#pragma unroll
      for (int reg = 0; reg < 4; ++reg)
        *(float*)(sm + Z1_O + ((size_t)(r0 + reg) * 116 + col) * 4) =
            fmaxf(a1[reg] + bb, 0.f);
    }
  }
  for (int i = t; i < 100 * 64; i += NTHR) { // stage W2s [100][64]
    int rr = i >> 6, c = i & 63;
    *(float*)(sm + W2S_O + ((size_t)rr * 64 + c) * 4) =
        (c < 60) ? Wc2[(size_t)rr * 60 + c] : 0.f;
  }
  if (t < 64) *(float*)(sm + W3S_O + (size_t)t * 4) = (t < 60) ? Wc3[t] : 0.f;
  __syncthreads();
  if (t < 128) {                             // L2: Z2 = relu(Z1@Wc2+bc2)
    int r2 = (t >> 3) * 2;
    int c8 = (t & 7) * 8;
    float a2[2][8];
#pragma unroll
    for (int i = 0; i < 2; ++i)
#pragma unroll
      for (int j = 0; j < 8; ++j) a2[i][j] = 0.f;
    const float* Z1p = (const float*)(sm + Z1_O);
    const float* W2p = (const float*)(sm + W2S_O);
#pragma unroll 4
    for (int k = 0; k < 100; ++k) {
      float x0 = Z1p[(size_t)r2 * 116 + k], x1 = Z1p[(size_t)(r2 + 1) * 116 + k];
      float4 wA = *(const float4*)(W2p + (size_t)k * 64 + c8);
      float4 wB = *(const float4*)(W2p + (size_t)k * 64 + c8 + 4);
      float wv[8] = {wA.x, wA.y, wA.z, wA.w, wB.x, wB.y, wB.z, wB.w};
#pragma unroll
      for (int j = 0; j < 8; ++j) { a2[0][j] += x0 * wv[j]; a2[1][j] += x1 * wv[j]; }
    }
    float* Z2p = (float*)(sm + Z2_O);
#pragma unroll
    for (int j = 0; j < 8; ++j) {
      int c = c8 + j;
      float bb = (c < 60) ? bc2[c] : 0.f;
      Z2p[(size_t)r2 * 64 + c] = fmaxf(a2[0][j] + bb, 0.f);
      Z2p[(size_t)(r2 + 1) * 64 + c] = fmaxf(a2[1][j] + bb, 0.f);
    }
  }
  __syncthreads();
  if (t < 32) {                              // L3: out = Z2 . Wc3 + bc3
    const float* Z2p = (const float*)(sm + Z2_O);
    const float* w3p = (const float*)(sm + W3S_O);
    float acc3 = bc3[0];
#pragma unroll
    for (int k = 0; k < 60; ++k) acc3 += Z2p[(size_t)t * 64 + k] * w3p[k];
    out[(size_t)g * 32 + t] = acc3;
  }
}

extern "C" void kernel_launch(void* const* d_in, const int* in_sizes, int n_in,
                              void* d_out, int out_size, void* d_ws, size_t ws_size,
                              hipStream_t stream) {
  (void)in_sizes; (void)n_in; (void)out_size; (void)ws_size;
  const float* x1  = (const float*)d_in[0];
  const int*   ei1 = (const int*)d_in[1];
  const float* ea1 = (const float*)d_in[2];
  const float* x2  = (const float*)d_in[3];
  const int*   ei2 = (const int*)d_in[4];
  const float* ea2 = (const float*)d_in[5];
  const float* W1  = (const float*)d_in[6];
  const float* b1  = (const float*)d_in[7];
  const float* W4  = (const float*)d_in[8];
  const float* b4  = (const float*)d_in[9];
  const float* Wc1 = (const float*)d_in[10];
  const float* bc1 = (const float*)d_in[11];
  const float* Wc2 = (const float*)d_in[12];
  const float* bc2 = (const float*)d_in[13];
  const float* Wc3 = (const float*)d_in[14];
  const float* bc3 = (const float*)d_in[15];

  char* ws = (char*)d_ws;
  float* dinv  = (float*)(ws + OFF_DINV);
  short* arena = (short*)(ws + OFF_ARENA);
  short* Wc1bT = (short*)(ws + OFF_WC1BT);
  short* W4bT  = (short*)(ws + OFF_W4BT);
  short* Lb    = (short*)(ws + OFF_LB);
  float* Y     = (float*)(ws + OFF_Y);
  float* out   = (float*)d_out;

  // L1: per-graph degree -> dinv (weight conv moved into L2's tail)
  k_deg<<<128, 256, 0, stream>>>(ei1, ea1, ei2, ea2, dinv);
  // L2: Laplacian build || gemm1 (prefetched, W1-direct B) || weight conv
  k_build_gemm1<<<1814, 256, 0, stream>>>(ei1, ea1, ei2, ea2, dinv, Lb,
                                          x1, x2, W1, Wc1, W4, Y, arena,
                                          Wc1bT, W4bT);
  // L3: per-graph mega-block, 1024 threads (16 waves) + reg-prefetch
  k_mega<<<128, NTHR, 0, stream>>>(Lb, arena, Y, W4bT, Wc1bT,
                                   b1, b4, bc1, Wc2, bc2, Wc3, bc3, out);
}

// Round 7
// 208.115 us; speedup vs baseline: 1.1572x; 1.1572x over previous
//
#include <hip/hip_runtime.h>
#include <hip/hip_bf16.h>

#define NN 268
#define NE 8192
#define KP 288   // padded node dim (268 -> 288)

typedef short short8 __attribute__((ext_vector_type(8)));   // 8 bf16 = 4 VGPR
typedef short short4v __attribute__((ext_vector_type(4)));  // 4 bf16 = 8B
typedef float f32x4 __attribute__((ext_vector_type(4)));

__device__ __forceinline__ short f2bf(float f) {
  __hip_bfloat16 h = __float2bfloat16(f);
  return *reinterpret_cast<short*>(&h);
}

// ---------------------------------------------------------------------------
// Workspace (bytes). Peak 51,444,736.
//   OFF_DINV  dinv  f32 [128][272]           139,264
//   OFF_ARENA Y2t   bf16[128][64][288]     4,718,592  (gemm1 out, mega in)
//   OFF_WBT   WbT   bf16[192][288]           110,592  (prep out, gemm1 in)
//   OFF_WC1BT Wc1bT bf16[112][288]            64,512  (build tail out, mega in)
//   OFF_W4BT  W4bT  bf16[96][64]              12,288  (build tail out, mega in)
//   OFF_LB    Lb    bf16[128][272][288]   20,054,016
//   OFF_Y     Y     f32 [128][268][192]   26,345,472
// Math chain BIT-IDENTICAL to round-1/5. Round-7 = round-5 structure +
//   (a) gemm1 k-loop A/B register prefetch (WbT source KEPT — R6's regression
//       was the W1-direct staging, not the prefetch),
//   (b) prep slimmed to deg + WbT; Wc1bT/W4bT conversion moved to build tail,
//   (c) mega reverted to the measured-best 512-thread round-5 version.
// ---------------------------------------------------------------------------
#define OFF_DINV  0
#define OFF_ARENA 139264
#define ARENA_SLAB_S 18432   // shorts per graph: Y2t [64][288]
#define OFF_WBT   4857856
#define OFF_WC1BT 4968448
#define OFF_W4BT  5032960
#define OFF_LB    5045248
#define OFF_Y     25099264

// ---------------------------------------------------------------------------
// K1: prep. 344 blocks: [0,128) per-graph degree -> dinv; [128,344) WbT
// conversion (consumed by gemm1 next launch).
// ---------------------------------------------------------------------------
__global__ __launch_bounds__(256) void k_prep(
    const int* __restrict__ ei1, const float* __restrict__ ea1,
    const int* __restrict__ ei2, const float* __restrict__ ea2,
    const float* __restrict__ W1, short* __restrict__ WbT,
    float* __restrict__ dinv) {
  int t = threadIdx.x;
  int b = blockIdx.x;
  if (b < 128) {
    int g = b;
    const int* ei = (g < 64) ? (ei1 + (size_t)g * 2 * NE) : (ei2 + (size_t)(g - 64) * 2 * NE);
    const float* ea = (g < 64) ? (ea1 + (size_t)g * NE) : (ea2 + (size_t)(g - 64) * NE);
    __shared__ unsigned degL[NN];
    for (int n = t; n < NN; n += 256) degL[n] = 0u;
    __syncthreads();
#pragma unroll 4
    for (int e = t; e < NE; e += 256) {
      int s = ei[e], d = ei[NE + e];
      float w = ea[e];
      if (s != d) atomicAdd(&degL[s], (unsigned)lrintf(w * 1048576.f));
    }
    __syncthreads();
    for (int n = t; n < 272; n += 256) {
      float r = 0.f;
      if (n < NN) {
        unsigned v = degL[n];
        if (v) r = rsqrtf((float)v * (1.f / 1048576.f));
      }
      dinv[(size_t)g * 272 + n] = r;
    }
  } else {
    int idx = (b - 128) * 256 + t;  // 0..55295 = 192*288
    int n = idx / KP, kp = idx - n * KP;
    int kb = n >> 6, j = n & 63;
    float v = (kp < 268) ? W1[((size_t)kb * 268 + kp) * 64 + j] : 0.f;
    WbT[idx] = f2bf(v);
  }
}

// ---------------------------------------------------------------------------
// K2: fused Laplacian build + gemm1 + Wc1bT/W4bT tail. 1814 blocks.
//  [0,640):     gemm1 (MFMA), WbT-sourced B, A+B REGISTER PREFETCH (new).
//  [640,1664):  Laplacian 34-row tiles (round-1 verbatim).
//  [1664,1814): Wc1bT / W4bT conversion (consumed by k_mega, next launch).
// ---------------------------------------------------------------------------
__global__ __launch_bounds__(256) void k_build_gemm1(
    const int* __restrict__ ei1, const float* __restrict__ ea1,
    const int* __restrict__ ei2, const float* __restrict__ ea2,
    const float* __restrict__ dinv_all, short* __restrict__ Lb,
    const float* __restrict__ x1, const float* __restrict__ x2,
    const short* __restrict__ WbT, const float* __restrict__ Wc1,
    const float* __restrict__ W4, float* __restrict__ Y,
    short* __restrict__ Y2t, short* __restrict__ Wc1bT,
    short* __restrict__ W4bT) {
  __shared__ __align__(16) char smem[34 * 288 * 4 + 272 * 4];  // 40,256 B
  int t = threadIdx.x;
  int bx = blockIdx.x;
  if (bx < 640) {
    // ===================== gemm1 (MFMA, A/B prefetched) ====================
    int xcd = bx & 7, rest = bx >> 3;       // rest 0..79
    int g = xcd + 8 * (rest / 5);           // graph on XCD g&7
    int m0 = (rest % 5) * 64;
    const float* A32 = (g < 64) ? (x1 + (size_t)g * NN * 268)
                                : (x2 + (size_t)(g - 64) * NN * 268);
    float* Yg = Y + (size_t)g * NN * 192;
    short* Y2tg = Y2t + (size_t)g * ARENA_SLAB_S;
    short (*As)[40] = (short(*)[40])smem;                     //  5,120 B
    short (*Bs)[40] = (short(*)[40])(smem + 5120);            // 15,360 B
    int w = t >> 6, lane = t & 63;
    int quad = lane >> 4, l16 = lane & 15;
    int mh = w & 1, nh = w >> 1;
    f32x4 acc[2][6];
#pragma unroll
    for (int mi = 0; mi < 2; ++mi)
#pragma unroll
      for (int ni = 0; ni < 6; ++ni) acc[mi][ni] = (f32x4){0.f, 0.f, 0.f, 0.f};

    int sr = t >> 2, sko = (t & 3) * 8;
    float4 pva, pvb;
    short8 pB[3];
    auto loadA = [&](int K0) {
      int row = m0 + sr, k = K0 + sko;
      pva = make_float4(0.f, 0.f, 0.f, 0.f); pvb = pva;
      if (row < NN && k < 268) pva = *(const float4*)(A32 + (size_t)row * 268 + k);
      if (row < NN && k + 4 < 268) pvb = *(const float4*)(A32 + (size_t)row * 268 + k + 4);
    };
    auto loadB = [&](int K0) {
#pragma unroll
      for (int i = 0; i < 3; ++i)
        pB[i] = *(const short8*)(WbT + (size_t)(sr + i * 64) * KP + K0 + sko);
    };
    loadA(0); loadB(0);
    for (int k0 = 0; k0 < KP; k0 += 32) {
      {
        short8 s;
        const float* fa = (const float*)&pva;
        const float* fb = (const float*)&pvb;
#pragma unroll
        for (int j = 0; j < 4; ++j) { s[j] = f2bf(fa[j]); s[4 + j] = f2bf(fb[j]); }
        *(short8*)(&As[sr][sko]) = s;
      }
#pragma unroll
      for (int i = 0; i < 3; ++i)
        *(short8*)(&Bs[sr + i * 64][sko]) = pB[i];
      __syncthreads();
      if (k0 + 32 < KP) { loadA(k0 + 32); loadB(k0 + 32); }  // hides under MFMA
      short8 af[2], bfr[6];
#pragma unroll
      for (int mi = 0; mi < 2; ++mi)
        af[mi] = *(const short8*)(&As[(mh * 2 + mi) * 16 + l16][quad * 8]);
#pragma unroll
      for (int ni = 0; ni < 6; ++ni)
        bfr[ni] = *(const short8*)(&Bs[(nh * 6 + ni) * 16 + l16][quad * 8]);
#pragma unroll
      for (int mi = 0; mi < 2; ++mi)
#pragma unroll
        for (int ni = 0; ni < 6; ++ni)
          acc[mi][ni] = __builtin_amdgcn_mfma_f32_16x16x32_bf16(af[mi], bfr[ni], acc[mi][ni], 0, 0, 0);
      __syncthreads();
    }
    // C/D: col = lane&15, row = quad*4 + reg
#pragma unroll
    for (int mi = 0; mi < 2; ++mi) {
      int rbase = m0 + (mh * 2 + mi) * 16 + quad * 4;
#pragma unroll
      for (int reg = 0; reg < 4; ++reg) {
        int row = rbase + reg;
        if (row < NN) {
#pragma unroll
          for (int ni = 0; ni < 6; ++ni) {
            int col = (nh * 6 + ni) * 16 + l16;
            Yg[(size_t)row * 192 + col] = acc[mi][ni][reg];
          }
        }
      }
      if (rbase < NN) {  // rbase % 4 == 0, never straddles 268
#pragma unroll
        for (int ni = 0; ni < 6; ++ni) {
          int col = (nh * 6 + ni) * 16 + l16;
          if (col >= 128) {
            short4v p;
#pragma unroll
            for (int reg = 0; reg < 4; ++reg) p[reg] = f2bf(acc[mi][ni][reg]);
            *(short4v*)(Y2tg + (size_t)(col - 128) * KP + rbase) = p;
          }
        }
      }
    }
  } else if (bx < 1664) {
    // ===================== Laplacian build =====================
    int l = bx - 640;                // 0..1023 = 8 xcd * 16 g * 8 tiles
    int xcd = l & 7, rest = l >> 3;  // rest 0..127
    int g = xcd + 8 * (rest & 15);
    int tile = rest >> 4;            // 0..7
    int r0 = tile * 34;
    const int* ei = (g < 64) ? (ei1 + (size_t)g * 2 * NE) : (ei2 + (size_t)(g - 64) * 2 * NE);
    const float* ea = (g < 64) ? (ea1 + (size_t)g * NE) : (ea2 + (size_t)(g - 64) * NE);
    int* LrowI = (int*)smem;                      // 34*288 ints = 39,168 B
    float* dv = (float*)(smem + 39168);           // 272 floats
    for (int i = t; i < 34 * 288; i += 256) LrowI[i] = 0;
    for (int i = t; i < 272; i += 256) dv[i] = dinv_all[(size_t)g * 272 + i];
    __syncthreads();
#pragma unroll 8
    for (int e = t; e < NE; e += 256) {
      int d = ei[NE + e];
      int s = ei[e];
      float w = ea[e];
      if (d >= r0 && d < r0 + 34 && s != d) {
        atomicAdd(&LrowI[(d - r0) * 288 + s],
                  (int)lrintf(-dv[s] * w * dv[d] * 16777216.f));  // native ds_add
      }
    }
    __syncthreads();
    short* Lbg = Lb + (size_t)g * 272 * KP + (size_t)r0 * KP;
    for (int i = t; i < 34 * 288; i += 256)
      Lbg[i] = f2bf((float)LrowI[i] * (1.f / 16777216.f));
  } else {
    // ===================== Wc1bT / W4bT tail (mega inputs) =================
    int idx = (bx - 1664) * 256 + t;  // 0..38399
    if (idx < 112 * KP) {
      int n = idx / KP, k = idx - n * KP;
      float v = (n < 100 && k < 268) ? Wc1[(size_t)k * 100 + n] : 0.f;
      Wc1bT[idx] = f2bf(v);
    } else {
      int i4 = idx - 112 * KP;       // 0..6143
      int n = i4 >> 6, k = i4 & 63;  // n in [0,96), k in [0,64)
      W4bT[i4] = f2bf(W4[(((size_t)(n >> 5)) * 64 + k) * 32 + (n & 31)]);
    }
  }
}

// ---------------------------------------------------------------------------
// K3: MEGA — round-5 verbatim (measured 49.7 us; 1024-thread variant of
// round 6 regressed, reverted). 512 threads (8 waves), register double-buffer
// of global L A-fragments + residual-Y prefetch. 128 blocks, 111,616 B LDS.
//   P0 Y2t->LDS   P1 Ut=bf16(Y1+2*L@Y2)   P2 H1=relu(Y0-Y2+L@Ut+b1)
//   P3 Yb=H1@W4 -> Yg f32 + Yb2t LDS      P4 Ut2=bf16(Yb1+2*L@Yb2)
//   P5 H2=relu(Yb0-Yb2+L@Ut2+b4)          P6 classifier -> out
// ---------------------------------------------------------------------------
#define SP 296
#define YT2_O  0
#define H1N_O  0
#define UT_O   40960
#define UT2_O  40960
#define H2T_O  59904
#define W4S_O  78848
#define YBT_O  92672
#define Z1_O   0
#define W2S_O  14848
#define Z2_O   78848
#define W3S_O  87040
#define SM_SZ  111616
#define NW     8       // waves per mega block
#define NTHR   512

__device__ __forceinline__ void load_a9(const short* __restrict__ Lbg,
                                        int mt, int l16, int quad, short8* a9) {
  const short* Arow = Lbg + (size_t)(mt * 16 + l16) * KP + quad * 8;
#pragma unroll
  for (int k = 0; k < 9; ++k) a9[k] = *(const short8*)(Arow + k * 32);
}

template <int NTN>
__device__ __forceinline__ void cheb_mm_pre(const short8* a9,
                                            const char* B0, int l16, int quad,
                                            f32x4* acc) {
#pragma unroll
  for (int k = 0; k < 9; ++k) {
#pragma unroll
    for (int nt = 0; nt < NTN; ++nt) {
      short8 bf = *(const short8*)(B0 +
          ((size_t)(nt * 16 + l16) * SP + k * 32 + quad * 8) * 2);
      acc[nt] = __builtin_amdgcn_mfma_f32_16x16x32_bf16(a9[k], bf, acc[nt], 0, 0, 0);
    }
  }
}

__global__ __launch_bounds__(NTHR, 1) void k_mega(
    const short* __restrict__ Lb, const short* __restrict__ arena,
    float* __restrict__ Y, const short* __restrict__ W4bT,
    const short* __restrict__ Wc1bT,
    const float* __restrict__ b1, const float* __restrict__ b4,
    const float* __restrict__ bc1, const float* __restrict__ Wc2,
    const float* __restrict__ bc2, const float* __restrict__ Wc3,
    const float* __restrict__ bc3, float* __restrict__ out) {
  __shared__ __align__(16) char sm[SM_SZ];
  int g = blockIdx.x;
  int t = threadIdx.x;
  int w = t >> 6, lane = t & 63;
  int quad = lane >> 4, l16 = lane & 15;
  const short* Lbg = Lb + (size_t)g * 272 * KP;
  const short* Y2tg = arena + (size_t)g * ARENA_SLAB_S;
  float* Yg = Y + (size_t)g * NN * 192;

  // ---- P0: Y2t -> LDS [64][SP]; cols >=268 forced to 0 (poison-safe) ----
  for (int i = t; i < 64 * 37; i += NTHR) {
    int r = i / 37, c = (i - r * 37) * 8;
    short8 v = {0, 0, 0, 0, 0, 0, 0, 0};
    if (c < 264) {
      v = *(const short8*)(Y2tg + (size_t)r * KP + c);
    } else if (c == 264) {
      v = *(const short8*)(Y2tg + (size_t)r * KP + 264);
      v[4] = 0; v[5] = 0; v[6] = 0; v[7] = 0;
    }
    *(short8*)(sm + YT2_O + ((size_t)r * SP + c) * 2) = v;
  }
  // zero Ut node-pad cols 268..287 (Ut region disjoint of Y2t)
  for (int i = t; i < 64 * 20; i += NTHR) {
    int f = i / 20, d = 268 + (i - f * 20);
    *(short*)(sm + UT_O + ((size_t)f * SP + d) * 2) = 0;
  }
  __syncthreads();

  // ---- P1: Ut[f][d] = bf16(Y1[d][f] + 2*(L@Y2)[d][f]) ----
  {
    short8 ac[9], an[9];
    int mt = w;
    if (mt < 17) load_a9(Lbg, mt, l16, quad, ac);
    for (; mt < 17; mt += NW) {
      if (mt + NW < 17) load_a9(Lbg, mt + NW, l16, quad, an);
      int dbase = mt * 16 + quad * 4;
      float yr[4][4];
      if (dbase < NN) {
#pragma unroll
        for (int nt = 0; nt < 4; ++nt)
#pragma unroll
          for (int reg = 0; reg < 4; ++reg)
            yr[nt][reg] = Yg[(size_t)(dbase + reg) * 192 + 64 + nt * 16 + l16];
      }
      f32x4 acc[4];
#pragma unroll
      for (int nt = 0; nt < 4; ++nt) acc[nt] = (f32x4){0.f, 0.f, 0.f, 0.f};
      cheb_mm_pre<4>(ac, sm + YT2_O, l16, quad, acc);
      if (dbase < NN) {
#pragma unroll
        for (int nt = 0; nt < 4; ++nt) {
          int f = nt * 16 + l16;
          short4v p;
#pragma unroll
          for (int reg = 0; reg < 4; ++reg)
            p[reg] = f2bf(yr[nt][reg] + 2.f * acc[nt][reg]);
          *(short4v*)(sm + UT_O + ((size_t)f * SP + dbase) * 2) = p;
        }
      }
      if (mt + NW < 17) {
#pragma unroll
        for (int k = 0; k < 9; ++k) ac[k] = an[k];
      }
    }
  }
  __syncthreads();

  // ---- P2: H1n[d][f] = relu(Y0 - Y2 + (L@Ut)[d][f] + b1[f]), stride 72 ----
  {
    short8 ac[9], an[9];
    int mt = w;
    if (mt < 17) load_a9(Lbg, mt, l16, quad, ac);
    for (; mt < 17; mt += NW) {
      if (mt + NW < 17) load_a9(Lbg, mt + NW, l16, quad, an);
      int dbase = mt * 16 + quad * 4;
      float yr0[4][4], yr2[4][4];
      if (dbase < NN) {
#pragma unroll
        for (int nt = 0; nt < 4; ++nt)
#pragma unroll
          for (int reg = 0; reg < 4; ++reg) {
            int f = nt * 16 + l16;
            yr0[nt][reg] = Yg[(size_t)(dbase + reg) * 192 + f];
            yr2[nt][reg] = Yg[(size_t)(dbase + reg) * 192 + 128 + f];
          }
      }
      f32x4 acc[4];
#pragma unroll
      for (int nt = 0; nt < 4; ++nt) acc[nt] = (f32x4){0.f, 0.f, 0.f, 0.f};
      cheb_mm_pre<4>(ac, sm + UT_O, l16, quad, acc);
      if (dbase < NN) {
#pragma unroll
        for (int nt = 0; nt < 4; ++nt) {
          int f = nt * 16 + l16;
          float bb = b1[f];
#pragma unroll
          for (int reg = 0; reg < 4; ++reg) {
            int d = dbase + reg;
            float v = yr0[nt][reg] - yr2[nt][reg] + acc[nt][reg] + bb;
            *(short*)(sm + H1N_O + ((size_t)d * 72 + f) * 2) = f2bf(fmaxf(v, 0.f));
          }
        }
      }
      if (mt + NW < 17) {
#pragma unroll
        for (int k = 0; k < 9; ++k) ac[k] = an[k];
      }
    }
  }
  __syncthreads();

  // ---- P3: Yb^T[c][d] = (H1 @ W4)[d][c]; c<64 -> Yg[d][c] f32,
  //          c>=64 -> Yg[d][c+96] f32 + YBT (Yb2t bf16) ----
  for (int i = t; i < 96 * 8; i += NTHR) {  // stage W4s [96][72]
    int r = i >> 3, ko = (i & 7) * 8;
    *(short8*)(sm + W4S_O + ((size_t)r * 72 + ko) * 2) =
        *(const short8*)(W4bT + r * 64 + ko);
  }
  for (int i = t; i < 32 * 20; i += NTHR) { // zero YBT node-pads
    int f = i / 20, d = 268 + (i - f * 20);
    *(short*)(sm + YBT_O + ((size_t)f * SP + d) * 2) = 0;
  }
  __syncthreads();
  for (int id = w; id < 102; id += NW) {    // 6 c-tiles x 17 d-tiles
    int mt = id / 17, nt = id - mt * 17;
    f32x4 a1 = (f32x4){0.f, 0.f, 0.f, 0.f};
#pragma unroll
    for (int kc = 0; kc < 2; ++kc) {
      short8 af = *(const short8*)(sm + W4S_O +
          ((size_t)(mt * 16 + l16) * 72 + kc * 32 + quad * 8) * 2);
      short8 bf = *(const short8*)(sm + H1N_O +
          ((size_t)(nt * 16 + l16) * 72 + kc * 32 + quad * 8) * 2);
      a1 = __builtin_amdgcn_mfma_f32_16x16x32_bf16(af, bf, a1, 0, 0, 0);
    }
    int d = nt * 16 + l16;
    if (d < NN) {
      int c0 = mt * 16 + quad * 4;
#pragma unroll
      for (int reg = 0; reg < 4; ++reg) {
        int c = c0 + reg;
        float a = a1[reg];
        Yg[(size_t)d * 192 + ((c < 64) ? c : c + 96)] = a;
        if (c >= 64)
          *(short*)(sm + YBT_O + ((size_t)(c - 64) * SP + d) * 2) = f2bf(a);
      }
    }
  }
  __syncthreads();

  // ---- P4: Ut2[f][d] = bf16(Yb1[d][f] + 2*(L@Yb2)[d][f]) ----
  for (int i = t; i < 32 * 20; i += NTHR) {
    int f = i / 20, d = 268 + (i - f * 20);
    *(short*)(sm + UT2_O + ((size_t)f * SP + d) * 2) = 0;
  }
  __syncthreads();
  {
    short8 ac[9], an[9];
    int mt = w;
    if (mt < 17) load_a9(Lbg, mt, l16, quad, ac);
    for (; mt < 17; mt += NW) {
      if (mt + NW < 17) load_a9(Lbg, mt + NW, l16, quad, an);
      int dbase = mt * 16 + quad * 4;
      float yr[2][4];
      if (dbase < NN) {
#pragma unroll
        for (int nt = 0; nt < 2; ++nt)
#pragma unroll
          for (int reg = 0; reg < 4; ++reg)
            yr[nt][reg] = Yg[(size_t)(dbase + reg) * 192 + 32 + nt * 16 + l16];
      }
      f32x4 acc[2];
#pragma unroll
      for (int nt = 0; nt < 2; ++nt) acc[nt] = (f32x4){0.f, 0.f, 0.f, 0.f};
      cheb_mm_pre<2>(ac, sm + YBT_O, l16, quad, acc);
      if (dbase < NN) {
#pragma unroll
        for (int nt = 0; nt < 2; ++nt) {
          int f = nt * 16 + l16;
          short4v p;
#pragma unroll
          for (int reg = 0; reg < 4; ++reg)
            p[reg] = f2bf(yr[nt][reg] + 2.f * acc[nt][reg]);
          *(short4v*)(sm + UT2_O + ((size_t)f * SP + dbase) * 2) = p;
        }
      }
      if (mt + NW < 17) {
#pragma unroll
        for (int k = 0; k < 9; ++k) ac[k] = an[k];
      }
    }
  }
  __syncthreads();

  // ---- P5: H2T[f][d] = relu(Yb0 - Yb2 + (L@Ut2)[d][f] + b4[f]) ----
  for (int i = t; i < 32 * 20; i += NTHR) {
    int f = i / 20, d = 268 + (i - f * 20);
    *(short*)(sm + H2T_O + ((size_t)f * SP + d) * 2) = 0;
  }
  __syncthreads();
  {
    short8 ac[9], an[9];
    int mt = w;
    if (mt < 17) load_a9(Lbg, mt, l16, quad, ac);
    for (; mt < 17; mt += NW) {
      if (mt + NW < 17) load_a9(Lbg, mt + NW, l16, quad, an);
      int dbase = mt * 16 + quad * 4;
      float yr0[2][4], yr2[2][4];
      if (dbase < NN) {
#pragma unroll
        for (int nt = 0; nt < 2; ++nt)
#pragma unroll
          for (int reg = 0; reg < 4; ++reg) {
            int f = nt * 16 + l16;
            yr0[nt][reg] = Yg[(size_t)(dbase + reg) * 192 + f];
            yr2[nt][reg] = Yg[(size_t)(dbase + reg) * 192 + 160 + f];
          }
      }
      f32x4 acc[2];
#pragma unroll
      for (int nt = 0; nt < 2; ++nt) acc[nt] = (f32x4){0.f, 0.f, 0.f, 0.f};
      cheb_mm_pre<2>(ac, sm + UT2_O, l16, quad, acc);
      if (dbase < NN) {
#pragma unroll
        for (int nt = 0; nt < 2; ++nt) {
          int f = nt * 16 + l16;
          float bb = b4[f];
          short4v p;
#pragma unroll
          for (int reg = 0; reg < 4; ++reg) {
            float v = yr0[nt][reg] - yr2[nt][reg] + acc[nt][reg] + bb;
            p[reg] = f2bf(fmaxf(v, 0.f));
          }
          *(short4v*)(sm + H2T_O + ((size_t)f * SP + dbase) * 2) = p;
        }
      }
      if (mt + NW < 17) {
#pragma unroll
        for (int k = 0; k < 9; ++k) ac[k] = an[k];
      }
    }
  }
  __syncthreads();

  // ---- P6: classifier. L1: MFMA 32x112 K=288 (A=H2T LDS, B=Wc1bT global) ----
  for (int id = w; id < 14; id += NW) {     // 2 m-tiles x 7 n-tiles
    int mt = id & 1, nt = id >> 1;
    f32x4 a1 = (f32x4){0.f, 0.f, 0.f, 0.f};
#pragma unroll
    for (int k = 0; k < 9; ++k) {
      short8 af = *(const short8*)(sm + H2T_O +
          ((size_t)(mt * 16 + l16) * SP + k * 32 + quad * 8) * 2);
      short8 bf = *(const short8*)(Wc1bT + (size_t)(nt * 16 + l16) * KP + k * 32 + quad * 8);
      a1 = __builtin_amdgcn_mfma_f32_16x16x32_bf16(af, bf, a1, 0, 0, 0);
    }
    int col = nt * 16 + l16;
    if (col < 100) {
      float bb = bc1[col];
      int r0 = mt * 16 + quad * 4;
#pragma unroll
      for (int reg = 0; reg < 4; ++reg)
        *(float*)(sm + Z1_O + ((size_t)(r0 + reg) * 116 + col) * 4) =
            fmaxf(a1[reg] + bb, 0.f);
    }
  }
  for (int i = t; i < 100 * 64; i += NTHR) { // stage W2s [100][64]
    int rr = i >> 6, c = i & 63;
    *(float*)(sm + W2S_O + ((size_t)rr * 64 + c) * 4) =
        (c < 60) ? Wc2[(size_t)rr * 60 + c] : 0.f;
  }
  if (t < 64) *(float*)(sm + W3S_O + (size_t)t * 4) = (t < 60) ? Wc3[t] : 0.f;
  __syncthreads();
  if (t < 128) {                             // L2: Z2 = relu(Z1@Wc2+bc2)
    int r2 = (t >> 3) * 2;
    int c8 = (t & 7) * 8;
    float a2[2][8];
#pragma unroll
    for (int i = 0; i < 2; ++i)
#pragma unroll
      for (int j = 0; j < 8; ++j) a2[i][j] = 0.f;
    const float* Z1p = (const float*)(sm + Z1_O);
    const float* W2p = (const float*)(sm + W2S_O);
#pragma unroll 4
    for (int k = 0; k < 100; ++k) {
      float x0 = Z1p[(size_t)r2 * 116 + k], x1 = Z1p[(size_t)(r2 + 1) * 116 + k];
      float4 wA = *(const float4*)(W2p + (size_t)k * 64 + c8);
      float4 wB = *(const float4*)(W2p + (size_t)k * 64 + c8 + 4);
      float wv[8] = {wA.x, wA.y, wA.z, wA.w, wB.x, wB.y, wB.z, wB.w};
#pragma unroll
      for (int j = 0; j < 8; ++j) { a2[0][j] += x0 * wv[j]; a2[1][j] += x1 * wv[j]; }
    }
    float* Z2p = (float*)(sm + Z2_O);
#pragma unroll
    for (int j = 0; j < 8; ++j) {
      int c = c8 + j;
      float bb = (c < 60) ? bc2[c] : 0.f;
      Z2p[(size_t)r2 * 64 + c] = fmaxf(a2[0][j] + bb, 0.f);
      Z2p[(size_t)(r2 + 1) * 64 + c] = fmaxf(a2[1][j] + bb, 0.f);
    }
  }
  __syncthreads();
  if (t < 32) {                              // L3: out = Z2 . Wc3 + bc3
    const float* Z2p = (const float*)(sm + Z2_O);
    const float* w3p = (const float*)(sm + W3S_O);
    float acc3 = bc3[0];
#pragma unroll
    for (int k = 0; k < 60; ++k) acc3 += Z2p[(size_t)t * 64 + k] * w3p[k];
    out[(size_t)g * 32 + t] = acc3;
  }
}

extern "C" void kernel_launch(void* const* d_in, const int* in_sizes, int n_in,
                              void* d_out, int out_size, void* d_ws, size_t ws_size,
                              hipStream_t stream) {
  (void)in_sizes; (void)n_in; (void)out_size; (void)ws_size;
  const float* x1  = (const float*)d_in[0];
  const int*   ei1 = (const int*)d_in[1];
  const float* ea1 = (const float*)d_in[2];
  const float* x2  = (const float*)d_in[3];
  const int*   ei2 = (const int*)d_in[4];
  const float* ea2 = (const float*)d_in[5];
  const float* W1  = (const float*)d_in[6];
  const float* b1  = (const float*)d_in[7];
  const float* W4  = (const float*)d_in[8];
  const float* b4  = (const float*)d_in[9];
  const float* Wc1 = (const float*)d_in[10];
  const float* bc1 = (const float*)d_in[11];
  const float* Wc2 = (const float*)d_in[12];
  const float* bc2 = (const float*)d_in[13];
  const float* Wc3 = (const float*)d_in[14];
  const float* bc3 = (const float*)d_in[15];

  char* ws = (char*)d_ws;
  float* dinv  = (float*)(ws + OFF_DINV);
  short* arena = (short*)(ws + OFF_ARENA);
  short* WbT   = (short*)(ws + OFF_WBT);
  short* Wc1bT = (short*)(ws + OFF_WC1BT);
  short* W4bT  = (short*)(ws + OFF_W4BT);
  short* Lb    = (short*)(ws + OFF_LB);
  float* Y     = (float*)(ws + OFF_Y);
  float* out   = (float*)d_out;

  // L1: per-graph degree -> dinv + WbT conversion (gemm1 input)
  k_prep<<<344, 256, 0, stream>>>(ei1, ea1, ei2, ea2, W1, WbT, dinv);
  // L2: Laplacian build || gemm1 (WbT B, A/B reg-prefetch) || Wc1bT/W4bT tail
  k_build_gemm1<<<1814, 256, 0, stream>>>(ei1, ea1, ei2, ea2, dinv, Lb,
                                          x1, x2, WbT, Wc1, W4, Y, arena,
                                          Wc1bT, W4bT);
  // L3: per-graph mega-block, 512 threads (round-5 verbatim, measured 49.7us)
  k_mega<<<128, NTHR, 0, stream>>>(Lb, arena, Y, W4bT, Wc1bT,
                                   b1, b4, bc1, Wc2, bc2, Wc3, bc3, out);
}